// Round 24
// baseline (171.388 us; speedup 1.0000x reference)
//
#include <hip/hip_runtime.h>
#include <hip/hip_bf16.h>

// Problem: x[4,2048,1024] f32; w_qkv[1024,3072]; w_out[1024,1024]; b_out[1024]
// out[4,2048,1024] f32.  HEADS=16, DH=64, scale=0.125 (x log2e folded into wqkvT).

typedef __attribute__((ext_vector_type(4))) float f32x4;
typedef __attribute__((ext_vector_type(16))) float f32x16;
typedef __attribute__((ext_vector_type(8))) unsigned short u16x8;
typedef __attribute__((ext_vector_type(4))) unsigned short u16x4;
typedef __attribute__((ext_vector_type(4))) unsigned int u32x4;
typedef __attribute__((ext_vector_type(8))) __bf16 bf16x8;

static __device__ __forceinline__ f32x4 mfma_bf16(u16x8 a, u16x8 b, f32x4 c) {
    return __builtin_amdgcn_mfma_f32_16x16x32_bf16(
        __builtin_bit_cast(bf16x8, a), __builtin_bit_cast(bf16x8, b), c, 0, 0, 0);
}
static __device__ __forceinline__ f32x16 mfma32(u16x8 a, u16x8 b, f32x16 c) {
    return __builtin_amdgcn_mfma_f32_32x32x16_bf16(
        __builtin_bit_cast(bf16x8, a), __builtin_bit_cast(bf16x8, b), c, 0, 0, 0);
}

static __device__ __forceinline__ unsigned short f2bf(float f) {
    unsigned int u = __builtin_bit_cast(unsigned int, f);
    u += 0x7fffu + ((u >> 16) & 1u);   // RNE
    return (unsigned short)(u >> 16);
}
static __device__ __forceinline__ unsigned int cvt_pk_bf16(float a, float b) {
    unsigned int r;
    asm("v_cvt_pk_bf16_f32 %0, %1, %2" : "=v"(r) : "v"(a), "v"(b));
    return r;
}
static __device__ __forceinline__ float fexp2(float x) {   // D = 2^S0
    float r;
    asm("v_exp_f32 %0, %1" : "=v"(r) : "v"(x));
    return r;
}
static __device__ __forceinline__ float frcp(float x) {
    float r;
    asm("v_rcp_f32 %0, %1" : "=v"(r) : "v"(x));
    return r;
}
typedef const __attribute__((address_space(1))) unsigned int* gp1_t;
typedef __attribute__((address_space(3))) unsigned int* lp3_t;
static __device__ __forceinline__ void gl_lds16(const void* g, void* l) {
    __builtin_amdgcn_global_load_lds((gp1_t)g, (lp3_t)l, 16, 0, 0);
}

// ------------- prep: x f32->bf16 + both weight transposes (one kernel) ------
__global__ void k_prep(const float* __restrict__ x, unsigned short* __restrict__ xb,
                       const float* __restrict__ w_qkv, unsigned short* __restrict__ wqkvT,
                       const float* __restrict__ w_out, unsigned short* __restrict__ woutT) {
    int blk = blockIdx.x, tid = threadIdx.x;
    if (blk < 2048) {
        int i = blk * 256 + tid;
        int stride = 2048 * 256;
        int n4 = 8192 * 1024 / 4;
        for (; i < n4; i += stride) {
            f32x4 v = ((const f32x4*)x)[i];
            u16x4 o;
            #pragma unroll
            for (int j = 0; j < 4; ++j) o[j] = f2bf(v[j]);
            ((u16x4*)xb)[i] = o;
        }
        return;
    }
    __shared__ float tile[32][33];
    const float* in; unsigned short* out; int R, C, scale_rows, c0, r0;
    float scale;
    if (blk < 5120) {
        int idx = blk - 2048;
        in = w_qkv; out = wqkvT; R = 1024; C = 3072;
        scale_rows = 1024; scale = 0.18033688f;   // 0.125 * log2(e) on Q cols
        c0 = (idx % 96) * 32; r0 = (idx / 96) * 32;
    } else {
        int idx = blk - 5120;
        in = w_out; out = woutT; R = 1024; C = 1024;
        scale_rows = 0; scale = 1.0f;
        c0 = (idx % 32) * 32; r0 = (idx / 32) * 32;
    }
    int tx = tid & 31, ty = tid >> 5;      // (32, 8)
    #pragma unroll
    for (int i = ty; i < 32; i += 8)
        tile[i][tx] = in[(size_t)(r0 + i) * C + c0 + tx];
    __syncthreads();
    #pragma unroll
    for (int i = ty; i < 32; i += 8) {
        float v = tile[tx][i];
        if (c0 + i < scale_rows) v *= scale;
        out[(size_t)(c0 + i) * R + r0 + tx] = f2bf(v);
    }
}

// -------- GEMM1 (QKV, fused-N): xb[8192][1024] @ wqkvT[3072][1024] ----------
// 256x384 tile, BK=64, 8 waves 4Mx2N (wave 64x192). Double-buffered, stage at
// tile start, ONE barrier per K-tile. j-loop software-pipelined.
__global__ __launch_bounds__(512, 1) void k_gemm1f(
    const unsigned short* __restrict__ A,
    const unsigned short* __restrict__ BT,
    unsigned short* __restrict__ qkv,
    unsigned short* __restrict__ VTs)
{
    __shared__ unsigned short As[2][256 * 64];   // 64 KB
    __shared__ unsigned short Bs[2][384 * 64];   // 96 KB
    const int K = 1024;
    const int tid = threadIdx.x, lane = tid & 63, wave = tid >> 6;

    int lin = blockIdx.y * 8 + blockIdx.x;        // 256 blocks
    int xcd = lin & 7, idx = lin >> 3;            // idx 0..31
    int by = xcd * 4 + (idx >> 3);                // 4 A-panels per XCD (2MB, L2)
    int bxg = idx & 7;
    const int m0 = by * 256, n0 = bxg * 384;

    const int wm = (wave >> 1) * 64, wn = (wave & 1) * 192;
    const int lr = lane & 15, half = lane >> 4;
    const int srow = lane >> 3, sslot = lane & 7;

    auto stage = [&](int buf, int t) {
        int k0 = t * 64;
        #pragma unroll
        for (int r = 0; r < 4; ++r) {
            int chunk = r * 8 + wave;
            int row = chunk * 8 + srow;
            int koff = (sslot ^ (row & 7)) * 8;
            gl_lds16(&A[(size_t)(m0 + row) * K + k0 + koff], &As[buf][chunk * 512]);
        }
        #pragma unroll
        for (int r = 0; r < 6; ++r) {
            int chunk = r * 8 + wave;
            int row = chunk * 8 + srow;
            int koff = (sslot ^ (row & 7)) * 8;
            gl_lds16(&BT[(size_t)(n0 + row) * K + k0 + koff], &Bs[buf][chunk * 512]);
        }
    };

    f32x4 acc[4][12] = {};

    stage(0, 0);
    asm volatile("s_waitcnt vmcnt(0)" ::: "memory");
    __builtin_amdgcn_s_barrier();

    for (int t = 0; t < 16; ++t) {
        const int cur = t & 1;
        if (t < 15) stage(cur ^ 1, t + 1);   // full-tile cover before its wait
        const unsigned short* Ab = As[cur];
        const unsigned short* Bb = Bs[cur];

        #pragma unroll
        for (int ks = 0; ks < 2; ++ks) {
            u16x8 af[4];
            #pragma unroll
            for (int i = 0; i < 4; ++i) {
                int ra = wm + i * 16 + lr;
                af[i] = *(const u16x8*)&Ab[ra * 64 + (((ks * 4 + half) ^ (ra & 7)) * 8)];
            }
            // software-pipelined j-loop: bfr one step ahead of its MFMAs
            u16x8 bfr = *(const u16x8*)&Bb[(wn + lr) * 64 +
                                           (((ks * 4 + half) ^ ((wn + lr) & 7)) * 8)];
            #pragma unroll
            for (int j = 0; j < 12; ++j) {
                u16x8 bfr_n;
                if (j < 11) {
                    int rb = wn + (j + 1) * 16 + lr;
                    bfr_n = *(const u16x8*)&Bb[rb * 64 + (((ks * 4 + half) ^ (rb & 7)) * 8)];
                }
                __builtin_amdgcn_s_setprio(1);
                #pragma unroll
                for (int i = 0; i < 4; ++i)
                    acc[i][j] = mfma_bf16(af[i], bfr, acc[i][j]);
                __builtin_amdgcn_s_setprio(0);
                bfr = bfr_n;
            }
        }

        asm volatile("s_waitcnt vmcnt(0) lgkmcnt(0)" ::: "memory");
        __builtin_amdgcn_s_barrier();
    }

    #pragma unroll
    for (int i = 0; i < 4; ++i) {
        int rowb = m0 + wm + i * 16 + half * 4;
        #pragma unroll
        for (int j = 0; j < 12; ++j) {
            int col = n0 + wn + j * 16 + lr;
            if (col < 2048) {
                #pragma unroll
                for (int r = 0; r < 4; ++r)
                    qkv[(size_t)(rowb + r) * 3072 + col] = f2bf(acc[i][j][r]);
            } else {
                int cj = col - 2048, h = cj >> 6, d = cj & 63;
                int b = rowb >> 11, n = rowb & 2047;
                u16x4 p;
                #pragma unroll
                for (int r = 0; r < 4; ++r) p[r] = f2bf(acc[i][j][r]);
                *(u16x4*)&VTs[((size_t)((b * 16 + h) * 64 + d)) * 2048 + n] = p;
            }
        }
    }
}

// ---------------- GEMM2 (out-proj): attn[8192][1024] @ woutT, +bias -> f32 ----
// Converted to the gemm1f schedule: 256x128 tile, BK=64, 8 waves 4Mx2N,
// DOUBLE-buffered 96KB LDS, burst-stage(t+1) at tile start, ONE
// vmcnt(0)+lgkmcnt(0)+barrier per K-tile (was 6 barriers/tile).
__global__ __launch_bounds__(512, 1) void k_gemm2(
    const unsigned short* __restrict__ A,
    const unsigned short* __restrict__ BT,
    const float* __restrict__ bias,
    float* __restrict__ outf)
{
    __shared__ unsigned short As[2][256 * 64];   // 64 KB
    __shared__ unsigned short Bs[2][128 * 64];   // 32 KB
    const int K = 1024;
    const int tid = threadIdx.x, lane = tid & 63, wave = tid >> 6;

    int lin = blockIdx.y * 8 + blockIdx.x;
    int virt = (lin & 7) * 32 + (lin >> 3);
    int bx = virt % 8, by = virt / 8;
    const int m0 = by * 256, n0 = bx * 128;

    const int wm = (wave >> 1) * 64, wn = (wave & 1) * 64;
    const int lr = lane & 15, half = lane >> 4;
    const int srow = lane >> 3, sslot = lane & 7;

    auto stage = [&](int buf, int t) {
        int k0 = t * 64;
        #pragma unroll
        for (int r = 0; r < 4; ++r) {
            int chunk = r * 8 + wave;
            int row = chunk * 8 + srow;
            int koff = (sslot ^ (row & 7)) * 8;
            gl_lds16(&A[(size_t)(m0 + row) * K + k0 + koff], &As[buf][chunk * 512]);
        }
        #pragma unroll
        for (int r = 0; r < 2; ++r) {
            int chunk = r * 8 + wave;
            int row = chunk * 8 + srow;
            int koff = (sslot ^ (row & 7)) * 8;
            gl_lds16(&BT[(size_t)(n0 + row) * K + k0 + koff], &Bs[buf][chunk * 512]);
        }
    };

    f32x4 acc[4][4] = {};

    stage(0, 0);
    asm volatile("s_waitcnt vmcnt(0)" ::: "memory");
    __builtin_amdgcn_s_barrier();

    for (int t = 0; t < 16; ++t) {
        const int cur = t & 1;
        if (t < 15) stage(cur ^ 1, t + 1);
        const unsigned short* Ab = As[cur];
        const unsigned short* Bb = Bs[cur];

        #pragma unroll
        for (int ks = 0; ks < 2; ++ks) {
            u16x8 af[4], bfr[4];
            #pragma unroll
            for (int i = 0; i < 4; ++i) {
                int ra = wm + i * 16 + lr;
                af[i] = *(const u16x8*)&Ab[ra * 64 + (((ks * 4 + half) ^ (ra & 7)) * 8)];
                int rb = wn + i * 16 + lr;
                bfr[i] = *(const u16x8*)&Bb[rb * 64 + (((ks * 4 + half) ^ (rb & 7)) * 8)];
            }
            __builtin_amdgcn_s_setprio(1);
            #pragma unroll
            for (int i = 0; i < 4; ++i)
                #pragma unroll
                for (int j = 0; j < 4; ++j)
                    acc[i][j] = mfma_bf16(af[i], bfr[j], acc[i][j]);
            __builtin_amdgcn_s_setprio(0);
        }

        asm volatile("s_waitcnt vmcnt(0) lgkmcnt(0)" ::: "memory");
        __builtin_amdgcn_s_barrier();
    }

    #pragma unroll
    for (int i = 0; i < 4; ++i)
        #pragma unroll
        for (int j = 0; j < 4; ++j)
            #pragma unroll
            for (int r = 0; r < 4; ++r) {
                int row = m0 + wm + i * 16 + half * 4 + r;
                int col = n0 + wn + j * 16 + lr;
                outf[(size_t)row * 1024 + col] = acc[i][j][r] + bias[col];
            }
}

// ---------------- flash attention: swapped-QK 32x32, 2 q-blocks/wave, --------
// KVBLK=128, ones-MFMA row sums, PV vf prefetch (R23 state).
__global__ __launch_bounds__(256, 2) void k_attn(
    const unsigned short* __restrict__ qkv,
    const unsigned short* __restrict__ VTs,
    unsigned short* __restrict__ attn)   // [8192][1024] bf16
{
    __shared__ unsigned short Kt[2][2][64 * 64];   // [buf][sub][.] 32 KB
    __shared__ unsigned short Vt[2][2][64 * 64];   // 32 KB
    const int tid = threadIdx.x, lane = tid & 63, wave = tid >> 6;

    int lin = blockIdx.y * 8 + blockIdx.x;    // 512 wgs, bijective XCD map
    int virt = (lin & 7) * 64 + (lin >> 3);
    int bh = virt >> 3;
    int q0 = (virt & 7) * 256 + wave * 64;

    const int lq = lane & 31;
    const int hi = lane >> 5;

    int b = bh >> 4, h = bh & 15;
    const unsigned short* Kq = qkv + (size_t)(b * 2048) * 3072 + 1024 + h * 64;
    const unsigned short* Vbase = VTs + (size_t)bh * 64 * 2048;

    u16x8 qfA[4], qfB[4];
    {
        const unsigned short* QrA = qkv + (size_t)(b * 2048 + q0 + lq) * 3072 + h * 64;
        const unsigned short* QrB = QrA + 32 * 3072;
        #pragma unroll
        for (int kk = 0; kk < 4; ++kk) {
            qfA[kk] = *(const u16x8*)&QrA[kk * 16 + hi * 8];
            qfB[kk] = *(const u16x8*)&QrB[kk * 16 + hi * 8];
        }
    }

    const int srow_in = lane >> 4, sslot = lane & 15;
    auto stage = [&](int buf, int j0) {      // stages BOTH 64-j sub-tiles
        #pragma unroll
        for (int jj = 0; jj < 2; ++jj) {
            #pragma unroll
            for (int c = 0; c < 2; ++c) {
                int chunk = wave * 2 + c;
                int row = chunk * 4 + srow_in;           // 0..31
                int v = sslot ^ (row & 15);
                int high = v >> 3, dsl = (v & 7) * 8;
                int js = j0 + jj * 64;
                gl_lds16(Kq + (size_t)(js + high * 32 + row) * 3072 + dsl,
                         &Kt[buf][jj][chunk * 512]);
                gl_lds16(Vbase + (size_t)(high * 32 + row) * 2048 + js + dsl,
                         &Vt[buf][jj][chunk * 512]);
            }
        }
    };

    f32x16 oA[2] = {}, oB[2] = {};
    f32x16 osumA = {}, osumB = {};
    const u16x8 onesf = {0x3F80, 0x3F80, 0x3F80, 0x3F80, 0x3F80, 0x3F80, 0x3F80, 0x3F80};

    stage(0, 0);
    __syncthreads();
    int cur = 0;

    for (int t = 0; t < 16; ++t) {
        if (t < 15) stage(cur ^ 1, (t + 1) * 128);

        #pragma unroll
        for (int jj = 0; jj < 2; ++jj) {
            // ---- QK: two independent chains share kf reads ----
            f32x16 sA[2] = {}, sB[2] = {};
            __builtin_amdgcn_s_setprio(1);
            #pragma unroll
            for (int jb = 0; jb < 2; ++jb) {
                u16x8 kf[4];
                #pragma unroll
                for (int kk = 0; kk < 4; ++kk) {
                    int s = (jb * 8 + kk * 2 + hi) ^ (lq & 15);
                    kf[kk] = *(const u16x8*)&Kt[cur][jj][lq * 128 + s * 8];
                }
                #pragma unroll
                for (int kk = 0; kk < 4; ++kk) sA[jb] = mfma32(kf[kk], qfA[kk], sA[jb]);
                #pragma unroll
                for (int kk = 0; kk < 4; ++kk) sB[jb] = mfma32(kf[kk], qfB[kk], sB[jb]);
            }
            __builtin_amdgcn_s_setprio(0);

            // ---- p = 2^s, pack to bf16 A-frags ----
            u16x8 paA[4], paB[4];
            #pragma unroll
            for (int kk = 0; kk < 4; ++kk) {
                const int jb = kk >> 1, e0 = (kk & 1) * 8;
                unsigned int w0 = cvt_pk_bf16(fexp2(sA[jb][e0 + 0]), fexp2(sA[jb][e0 + 1]));
                unsigned int w1 = cvt_pk_bf16(fexp2(sA[jb][e0 + 2]), fexp2(sA[jb][e0 + 3]));
                unsigned int w2 = cvt_pk_bf16(fexp2(sA[jb][e0 + 4]), fexp2(sA[jb][e0 + 5]));
                unsigned int w3 = cvt_pk_bf16(fexp2(sA[jb][e0 + 6]), fexp2(sA[jb][e0 + 7]));
                asm("v_permlane32_swap_b32 %0, %1" : "+v"(w0), "+v"(w2));
                asm("v_permlane32_swap_b32 %0, %1" : "+v"(w1), "+v"(w3));
                u32x4 w; w[0] = w0; w[1] = w1; w[2] = w2; w[3] = w3;
                paA[kk] = __builtin_bit_cast(u16x8, w);
            }
            #pragma unroll
            for (int kk = 0; kk < 4; ++kk) {
                const int jb = kk >> 1, e0 = (kk & 1) * 8;
                unsigned int w0 = cvt_pk_bf16(fexp2(sB[jb][e0 + 0]), fexp2(sB[jb][e0 + 1]));
                unsigned int w1 = cvt_pk_bf16(fexp2(sB[jb][e0 + 2]), fexp2(sB[jb][e0 + 3]));
                unsigned int w2 = cvt_pk_bf16(fexp2(sB[jb][e0 + 4]), fexp2(sB[jb][e0 + 5]));
                unsigned int w3 = cvt_pk_bf16(fexp2(sB[jb][e0 + 6]), fexp2(sB[jb][e0 + 7]));
                asm("v_permlane32_swap_b32 %0, %1" : "+v"(w0), "+v"(w2));
                asm("v_permlane32_swap_b32 %0, %1" : "+v"(w1), "+v"(w3));
                u32x4 w; w[0] = w0; w[1] = w1; w[2] = w2; w[3] = w3;
                paB[kk] = __builtin_bit_cast(u16x8, w);
            }

            // ---- PV merged: vf pair prefetched one kk ahead ----
            const unsigned short* Vp = Vt[cur][jj];
            u16x8 vf0 = *(const u16x8*)&Vp[lq * 128 + (((0 * 8 + 0 * 2 + hi)) ^ (lq & 15)) * 8];
            u16x8 vf1 = *(const u16x8*)&Vp[lq * 128 + (((1 * 8 + 0 * 2 + hi)) ^ (lq & 15)) * 8];
            __builtin_amdgcn_s_setprio(1);
            #pragma unroll
            for (int kk = 0; kk < 4; ++kk) {
                u16x8 nf0, nf1;
                if (kk < 3) {
                    int s0 = (0 * 8 + (kk + 1) * 2 + hi) ^ (lq & 15);
                    int s1 = (1 * 8 + (kk + 1) * 2 + hi) ^ (lq & 15);
                    nf0 = *(const u16x8*)&Vp[lq * 128 + s0 * 8];
                    nf1 = *(const u16x8*)&Vp[lq * 128 + s1 * 8];
                }
                osumA = mfma32(paA[kk], onesf, osumA);
                osumB = mfma32(paB[kk], onesf, osumB);
                oA[0] = mfma32(paA[kk], vf0, oA[0]);
                oB[0] = mfma32(paB[kk], vf0, oB[0]);
                oA[1] = mfma32(paA[kk], vf1, oA[1]);
                oB[1] = mfma32(paB[kk], vf1, oB[1]);
                vf0 = nf0; vf1 = nf1;
            }
            __builtin_amdgcn_s_setprio(0);
        }

        __syncthreads();
        cur ^= 1;
    }

    // ---- epilogue: normalize and store both q-blocks ----
    #pragma unroll
    for (int r = 0; r < 16; ++r) {
        int qrow = (r & 3) + 8 * (r >> 2) + 4 * hi;
        float iA = frcp(osumA[r]);
        float iB = frcp(osumB[r]);
        size_t roA = (size_t)(b * 2048 + q0 + qrow) * 1024 + h * 64;
        size_t roB = (size_t)(b * 2048 + q0 + 32 + qrow) * 1024 + h * 64;
        attn[roA + lq]      = f2bf(oA[0][r] * iA);
        attn[roA + 32 + lq] = f2bf(oA[1][r] * iA);
        attn[roB + lq]      = f2bf(oB[0][r] * iB);
        attn[roB + 32 + lq] = f2bf(oB[1][r] * iB);
    }
}

extern "C" void kernel_launch(void* const* d_in, const int* in_sizes, int n_in,
                              void* d_out, int out_size, void* d_ws, size_t ws_size,
                              hipStream_t stream) {
    const float* x     = (const float*)d_in[0];
    const float* w_qkv = (const float*)d_in[1];
    const float* w_out = (const float*)d_in[2];
    const float* b_out = (const float*)d_in[3];
    float* out = (float*)d_out;

    char* ws = (char*)d_ws;
    size_t off = 0;
    auto alloc = [&](size_t bytes) -> void* {
        void* p = ws + off;
        off += (bytes + 255) & ~(size_t)255;
        return p;
    };
    unsigned short* xb    = (unsigned short*)alloc(8192ull * 1024 * 2);  // x bf16; reused as attn-out
    unsigned short* wqkvT = (unsigned short*)alloc(3072ull * 1024 * 2);
    unsigned short* woutT = (unsigned short*)alloc(1024ull * 1024 * 2);
    unsigned short* qkv   = (unsigned short*)alloc(8192ull * 3072 * 2);
    unsigned short* VTs   = (unsigned short*)alloc(64ull * 2048 * 64 * 2);
    if (off > ws_size) return;

    k_prep<<<6144, 256, 0, stream>>>(x, xb, w_qkv, wqkvT, w_out, woutT);
    k_gemm1f<<<dim3(8, 32), 512, 0, stream>>>(xb, wqkvT, qkv, VTs);
    k_attn<<<dim3(8, 64), 256, 0, stream>>>(qkv, VTs, xb);
    k_gemm2<<<dim3(8, 32), 512, 0, stream>>>(xb, woutT, b_out, out);
}

// Round 25
// 168.374 us; speedup vs baseline: 1.0179x; 1.0179x over previous
//
#include <hip/hip_runtime.h>
#include <hip/hip_bf16.h>

// Problem: x[4,2048,1024] f32; w_qkv[1024,3072]; w_out[1024,1024]; b_out[1024]
// out[4,2048,1024] f32.  HEADS=16, DH=64, scale=0.125 (x log2e folded into wqkvT).
// Final configuration (R23): 169.1 us, absmax 1.95e-3.

typedef __attribute__((ext_vector_type(4))) float f32x4;
typedef __attribute__((ext_vector_type(16))) float f32x16;
typedef __attribute__((ext_vector_type(8))) unsigned short u16x8;
typedef __attribute__((ext_vector_type(4))) unsigned short u16x4;
typedef __attribute__((ext_vector_type(4))) unsigned int u32x4;
typedef __attribute__((ext_vector_type(8))) __bf16 bf16x8;

static __device__ __forceinline__ f32x4 mfma_bf16(u16x8 a, u16x8 b, f32x4 c) {
    return __builtin_amdgcn_mfma_f32_16x16x32_bf16(
        __builtin_bit_cast(bf16x8, a), __builtin_bit_cast(bf16x8, b), c, 0, 0, 0);
}
static __device__ __forceinline__ f32x16 mfma32(u16x8 a, u16x8 b, f32x16 c) {
    return __builtin_amdgcn_mfma_f32_32x32x16_bf16(
        __builtin_bit_cast(bf16x8, a), __builtin_bit_cast(bf16x8, b), c, 0, 0, 0);
}

static __device__ __forceinline__ unsigned short f2bf(float f) {
    unsigned int u = __builtin_bit_cast(unsigned int, f);
    u += 0x7fffu + ((u >> 16) & 1u);   // RNE
    return (unsigned short)(u >> 16);
}
static __device__ __forceinline__ unsigned int cvt_pk_bf16(float a, float b) {
    unsigned int r;
    asm("v_cvt_pk_bf16_f32 %0, %1, %2" : "=v"(r) : "v"(a), "v"(b));
    return r;
}
static __device__ __forceinline__ float fexp2(float x) {   // D = 2^S0
    float r;
    asm("v_exp_f32 %0, %1" : "=v"(r) : "v"(x));
    return r;
}
static __device__ __forceinline__ float frcp(float x) {
    float r;
    asm("v_rcp_f32 %0, %1" : "=v"(r) : "v"(x));
    return r;
}
typedef const __attribute__((address_space(1))) unsigned int* gp1_t;
typedef __attribute__((address_space(3))) unsigned int* lp3_t;
static __device__ __forceinline__ void gl_lds16(const void* g, void* l) {
    __builtin_amdgcn_global_load_lds((gp1_t)g, (lp3_t)l, 16, 0, 0);
}

// ------------- prep: x f32->bf16 + both weight transposes (one kernel) ------
__global__ void k_prep(const float* __restrict__ x, unsigned short* __restrict__ xb,
                       const float* __restrict__ w_qkv, unsigned short* __restrict__ wqkvT,
                       const float* __restrict__ w_out, unsigned short* __restrict__ woutT) {
    int blk = blockIdx.x, tid = threadIdx.x;
    if (blk < 2048) {
        int i = blk * 256 + tid;
        int stride = 2048 * 256;
        int n4 = 8192 * 1024 / 4;
        for (; i < n4; i += stride) {
            f32x4 v = ((const f32x4*)x)[i];
            u16x4 o;
            #pragma unroll
            for (int j = 0; j < 4; ++j) o[j] = f2bf(v[j]);
            ((u16x4*)xb)[i] = o;
        }
        return;
    }
    __shared__ float tile[32][33];
    const float* in; unsigned short* out; int R, C, scale_rows, c0, r0;
    float scale;
    if (blk < 5120) {
        int idx = blk - 2048;
        in = w_qkv; out = wqkvT; R = 1024; C = 3072;
        scale_rows = 1024; scale = 0.18033688f;   // 0.125 * log2(e) on Q cols
        c0 = (idx % 96) * 32; r0 = (idx / 96) * 32;
    } else {
        int idx = blk - 5120;
        in = w_out; out = woutT; R = 1024; C = 1024;
        scale_rows = 0; scale = 1.0f;
        c0 = (idx % 32) * 32; r0 = (idx / 32) * 32;
    }
    int tx = tid & 31, ty = tid >> 5;      // (32, 8)
    #pragma unroll
    for (int i = ty; i < 32; i += 8)
        tile[i][tx] = in[(size_t)(r0 + i) * C + c0 + tx];
    __syncthreads();
    #pragma unroll
    for (int i = ty; i < 32; i += 8) {
        float v = tile[tx][i];
        if (c0 + i < scale_rows) v *= scale;
        out[(size_t)(c0 + i) * R + r0 + tx] = f2bf(v);
    }
}

// -------- GEMM1 (QKV, fused-N): xb[8192][1024] @ wqkvT[3072][1024] ----------
// 256x384 tile, BK=64, 8 waves 4Mx2N (wave 64x192). Double-buffered, stage at
// tile start, ONE barrier per K-tile. j-loop software-pipelined.
__global__ __launch_bounds__(512, 1) void k_gemm1f(
    const unsigned short* __restrict__ A,
    const unsigned short* __restrict__ BT,
    unsigned short* __restrict__ qkv,
    unsigned short* __restrict__ VTs)
{
    __shared__ unsigned short As[2][256 * 64];   // 64 KB
    __shared__ unsigned short Bs[2][384 * 64];   // 96 KB
    const int K = 1024;
    const int tid = threadIdx.x, lane = tid & 63, wave = tid >> 6;

    int lin = blockIdx.y * 8 + blockIdx.x;        // 256 blocks
    int xcd = lin & 7, idx = lin >> 3;            // idx 0..31
    int by = xcd * 4 + (idx >> 3);                // 4 A-panels per XCD (2MB, L2)
    int bxg = idx & 7;
    const int m0 = by * 256, n0 = bxg * 384;

    const int wm = (wave >> 1) * 64, wn = (wave & 1) * 192;
    const int lr = lane & 15, half = lane >> 4;
    const int srow = lane >> 3, sslot = lane & 7;

    auto stage = [&](int buf, int t) {
        int k0 = t * 64;
        #pragma unroll
        for (int r = 0; r < 4; ++r) {
            int chunk = r * 8 + wave;
            int row = chunk * 8 + srow;
            int koff = (sslot ^ (row & 7)) * 8;
            gl_lds16(&A[(size_t)(m0 + row) * K + k0 + koff], &As[buf][chunk * 512]);
        }
        #pragma unroll
        for (int r = 0; r < 6; ++r) {
            int chunk = r * 8 + wave;
            int row = chunk * 8 + srow;
            int koff = (sslot ^ (row & 7)) * 8;
            gl_lds16(&BT[(size_t)(n0 + row) * K + k0 + koff], &Bs[buf][chunk * 512]);
        }
    };

    f32x4 acc[4][12] = {};

    stage(0, 0);
    asm volatile("s_waitcnt vmcnt(0)" ::: "memory");
    __builtin_amdgcn_s_barrier();

    for (int t = 0; t < 16; ++t) {
        const int cur = t & 1;
        if (t < 15) stage(cur ^ 1, t + 1);   // full-tile cover before its wait
        const unsigned short* Ab = As[cur];
        const unsigned short* Bb = Bs[cur];

        #pragma unroll
        for (int ks = 0; ks < 2; ++ks) {
            u16x8 af[4];
            #pragma unroll
            for (int i = 0; i < 4; ++i) {
                int ra = wm + i * 16 + lr;
                af[i] = *(const u16x8*)&Ab[ra * 64 + (((ks * 4 + half) ^ (ra & 7)) * 8)];
            }
            // software-pipelined j-loop: bfr one step ahead of its MFMAs
            u16x8 bfr = *(const u16x8*)&Bb[(wn + lr) * 64 +
                                           (((ks * 4 + half) ^ ((wn + lr) & 7)) * 8)];
            #pragma unroll
            for (int j = 0; j < 12; ++j) {
                u16x8 bfr_n;
                if (j < 11) {
                    int rb = wn + (j + 1) * 16 + lr;
                    bfr_n = *(const u16x8*)&Bb[rb * 64 + (((ks * 4 + half) ^ (rb & 7)) * 8)];
                }
                __builtin_amdgcn_s_setprio(1);
                #pragma unroll
                for (int i = 0; i < 4; ++i)
                    acc[i][j] = mfma_bf16(af[i], bfr, acc[i][j]);
                __builtin_amdgcn_s_setprio(0);
                bfr = bfr_n;
            }
        }

        asm volatile("s_waitcnt vmcnt(0) lgkmcnt(0)" ::: "memory");
        __builtin_amdgcn_s_barrier();
    }

    #pragma unroll
    for (int i = 0; i < 4; ++i) {
        int rowb = m0 + wm + i * 16 + half * 4;
        #pragma unroll
        for (int j = 0; j < 12; ++j) {
            int col = n0 + wn + j * 16 + lr;
            if (col < 2048) {
                #pragma unroll
                for (int r = 0; r < 4; ++r)
                    qkv[(size_t)(rowb + r) * 3072 + col] = f2bf(acc[i][j][r]);
            } else {
                int cj = col - 2048, h = cj >> 6, d = cj & 63;
                int b = rowb >> 11, n = rowb & 2047;
                u16x4 p;
                #pragma unroll
                for (int r = 0; r < 4; ++r) p[r] = f2bf(acc[i][j][r]);
                *(u16x4*)&VTs[((size_t)((b * 16 + h) * 64 + d)) * 2048 + n] = p;
            }
        }
    }
}

// ---------------- GEMM2 (out-proj): attn[8192][1024] @ woutT, +bias -> f32 ----
// R23-proven: 256x128, BK=64, 8 waves 4Mx2N, triple-buffer, counted vmcnt(6).
__global__ __launch_bounds__(512, 1) void k_gemm2(
    const unsigned short* __restrict__ A,
    const unsigned short* __restrict__ BT,
    const float* __restrict__ bias,
    float* __restrict__ outf)
{
    __shared__ unsigned short As[3][256 * 64];
    __shared__ unsigned short Bs[3][128 * 64];
    const int K = 1024;
    const int tid = threadIdx.x, lane = tid & 63, wave = tid >> 6;

    int lin = blockIdx.y * 8 + blockIdx.x;
    int virt = (lin & 7) * 32 + (lin >> 3);
    int bx = virt % 8, by = virt / 8;
    const int m0 = by * 256, n0 = bx * 128;

    const int wm = (wave >> 1) * 64, wn = (wave & 1) * 64;
    const int lr = lane & 15, half = lane >> 4;
    const int srow = lane >> 3, sslot = lane & 7;

    auto stage_sub = [&](int buf, int t, int h) {
        int k0 = t * 64;
        #pragma unroll
        for (int r = 0; r < 2; ++r) {
            int chunk = (h * 2 + r) * 8 + wave;
            int row = chunk * 8 + srow;
            int koff = (sslot ^ (row & 7)) * 8;
            gl_lds16(&A[(size_t)(m0 + row) * K + k0 + koff], &As[buf][chunk * 512]);
        }
        {
            int chunk = h * 8 + wave;
            int row = chunk * 8 + srow;
            int koff = (sslot ^ (row & 7)) * 8;
            gl_lds16(&BT[(size_t)(n0 + row) * K + k0 + koff], &Bs[buf][chunk * 512]);
        }
    };

    f32x4 acc[4][4] = {};

    stage_sub(0, 0, 0); stage_sub(0, 0, 1);
    stage_sub(1, 1, 0); stage_sub(1, 1, 1);
    asm volatile("s_waitcnt vmcnt(6)" ::: "memory");
    __builtin_amdgcn_s_barrier();

    for (int t = 0; t < 16; ++t) {
        const int cur = t % 3, nxt = (t + 2) % 3;
        const bool do_stage = (t + 2) < 16;
        const unsigned short* Ab = As[cur];
        const unsigned short* Bb = Bs[cur];

        #pragma unroll
        for (int ks = 0; ks < 2; ++ks) {
            u16x8 af[4], bfr[4];
            #pragma unroll
            for (int i = 0; i < 4; ++i) {
                int ra = wm + i * 16 + lr;
                af[i] = *(const u16x8*)&Ab[ra * 64 + (((ks * 4 + half) ^ (ra & 7)) * 8)];
                int rb = wn + i * 16 + lr;
                bfr[i] = *(const u16x8*)&Bb[rb * 64 + (((ks * 4 + half) ^ (rb & 7)) * 8)];
            }
            if (do_stage) stage_sub(nxt, t + 2, ks);
            if (ks == 1) {
                if (t < 14)       asm volatile("s_waitcnt vmcnt(6)" ::: "memory");
                else if (t == 14) asm volatile("s_waitcnt vmcnt(0)" ::: "memory");
            }
            __builtin_amdgcn_s_barrier();
            asm volatile("s_waitcnt lgkmcnt(0)" ::: "memory");
            __builtin_amdgcn_sched_barrier(0);
            __builtin_amdgcn_s_setprio(1);
            #pragma unroll
            for (int i = 0; i < 4; ++i)
                #pragma unroll
                for (int j = 0; j < 4; ++j)
                    acc[i][j] = mfma_bf16(af[i], bfr[j], acc[i][j]);
            __builtin_amdgcn_s_setprio(0);
            __builtin_amdgcn_s_barrier();
        }
    }

    #pragma unroll
    for (int i = 0; i < 4; ++i)
        #pragma unroll
        for (int j = 0; j < 4; ++j)
            #pragma unroll
            for (int r = 0; r < 4; ++r) {
                int row = m0 + wm + i * 16 + half * 4 + r;
                int col = n0 + wn + j * 16 + lr;
                outf[(size_t)row * 1024 + col] = acc[i][j][r] + bias[col];
            }
}

// ---------------- flash attention: swapped-QK 32x32, 2 q-blocks/wave, --------
// KVBLK=128, ones-MFMA row sums, PV vf prefetch (R23 state).
__global__ __launch_bounds__(256, 2) void k_attn(
    const unsigned short* __restrict__ qkv,
    const unsigned short* __restrict__ VTs,
    unsigned short* __restrict__ attn)   // [8192][1024] bf16
{
    __shared__ unsigned short Kt[2][2][64 * 64];   // [buf][sub][.] 32 KB
    __shared__ unsigned short Vt[2][2][64 * 64];   // 32 KB
    const int tid = threadIdx.x, lane = tid & 63, wave = tid >> 6;

    int lin = blockIdx.y * 8 + blockIdx.x;    // 512 wgs, bijective XCD map
    int virt = (lin & 7) * 64 + (lin >> 3);
    int bh = virt >> 3;
    int q0 = (virt & 7) * 256 + wave * 64;

    const int lq = lane & 31;
    const int hi = lane >> 5;

    int b = bh >> 4, h = bh & 15;
    const unsigned short* Kq = qkv + (size_t)(b * 2048) * 3072 + 1024 + h * 64;
    const unsigned short* Vbase = VTs + (size_t)bh * 64 * 2048;

    u16x8 qfA[4], qfB[4];
    {
        const unsigned short* QrA = qkv + (size_t)(b * 2048 + q0 + lq) * 3072 + h * 64;
        const unsigned short* QrB = QrA + 32 * 3072;
        #pragma unroll
        for (int kk = 0; kk < 4; ++kk) {
            qfA[kk] = *(const u16x8*)&QrA[kk * 16 + hi * 8];
            qfB[kk] = *(const u16x8*)&QrB[kk * 16 + hi * 8];
        }
    }

    const int srow_in = lane >> 4, sslot = lane & 15;
    auto stage = [&](int buf, int j0) {      // stages BOTH 64-j sub-tiles
        #pragma unroll
        for (int jj = 0; jj < 2; ++jj) {
            #pragma unroll
            for (int c = 0; c < 2; ++c) {
                int chunk = wave * 2 + c;
                int row = chunk * 4 + srow_in;           // 0..31
                int v = sslot ^ (row & 15);
                int high = v >> 3, dsl = (v & 7) * 8;
                int js = j0 + jj * 64;
                gl_lds16(Kq + (size_t)(js + high * 32 + row) * 3072 + dsl,
                         &Kt[buf][jj][chunk * 512]);
                gl_lds16(Vbase + (size_t)(high * 32 + row) * 2048 + js + dsl,
                         &Vt[buf][jj][chunk * 512]);
            }
        }
    };

    f32x16 oA[2] = {}, oB[2] = {};
    f32x16 osumA = {}, osumB = {};
    const u16x8 onesf = {0x3F80, 0x3F80, 0x3F80, 0x3F80, 0x3F80, 0x3F80, 0x3F80, 0x3F80};

    stage(0, 0);
    __syncthreads();
    int cur = 0;

    for (int t = 0; t < 16; ++t) {
        if (t < 15) stage(cur ^ 1, (t + 1) * 128);

        #pragma unroll
        for (int jj = 0; jj < 2; ++jj) {
            // ---- QK: two independent chains share kf reads ----
            f32x16 sA[2] = {}, sB[2] = {};
            __builtin_amdgcn_s_setprio(1);
            #pragma unroll
            for (int jb = 0; jb < 2; ++jb) {
                u16x8 kf[4];
                #pragma unroll
                for (int kk = 0; kk < 4; ++kk) {
                    int s = (jb * 8 + kk * 2 + hi) ^ (lq & 15);
                    kf[kk] = *(const u16x8*)&Kt[cur][jj][lq * 128 + s * 8];
                }
                #pragma unroll
                for (int kk = 0; kk < 4; ++kk) sA[jb] = mfma32(kf[kk], qfA[kk], sA[jb]);
                #pragma unroll
                for (int kk = 0; kk < 4; ++kk) sB[jb] = mfma32(kf[kk], qfB[kk], sB[jb]);
            }
            __builtin_amdgcn_s_setprio(0);

            // ---- p = 2^s, pack to bf16 A-frags ----
            u16x8 paA[4], paB[4];
            #pragma unroll
            for (int kk = 0; kk < 4; ++kk) {
                const int jb = kk >> 1, e0 = (kk & 1) * 8;
                unsigned int w0 = cvt_pk_bf16(fexp2(sA[jb][e0 + 0]), fexp2(sA[jb][e0 + 1]));
                unsigned int w1 = cvt_pk_bf16(fexp2(sA[jb][e0 + 2]), fexp2(sA[jb][e0 + 3]));
                unsigned int w2 = cvt_pk_bf16(fexp2(sA[jb][e0 + 4]), fexp2(sA[jb][e0 + 5]));
                unsigned int w3 = cvt_pk_bf16(fexp2(sA[jb][e0 + 6]), fexp2(sA[jb][e0 + 7]));
                asm("v_permlane32_swap_b32 %0, %1" : "+v"(w0), "+v"(w2));
                asm("v_permlane32_swap_b32 %0, %1" : "+v"(w1), "+v"(w3));
                u32x4 w; w[0] = w0; w[1] = w1; w[2] = w2; w[3] = w3;
                paA[kk] = __builtin_bit_cast(u16x8, w);
            }
            #pragma unroll
            for (int kk = 0; kk < 4; ++kk) {
                const int jb = kk >> 1, e0 = (kk & 1) * 8;
                unsigned int w0 = cvt_pk_bf16(fexp2(sB[jb][e0 + 0]), fexp2(sB[jb][e0 + 1]));
                unsigned int w1 = cvt_pk_bf16(fexp2(sB[jb][e0 + 2]), fexp2(sB[jb][e0 + 3]));
                unsigned int w2 = cvt_pk_bf16(fexp2(sB[jb][e0 + 4]), fexp2(sB[jb][e0 + 5]));
                unsigned int w3 = cvt_pk_bf16(fexp2(sB[jb][e0 + 6]), fexp2(sB[jb][e0 + 7]));
                asm("v_permlane32_swap_b32 %0, %1" : "+v"(w0), "+v"(w2));
                asm("v_permlane32_swap_b32 %0, %1" : "+v"(w1), "+v"(w3));
                u32x4 w; w[0] = w0; w[1] = w1; w[2] = w2; w[3] = w3;
                paB[kk] = __builtin_bit_cast(u16x8, w);
            }

            // ---- PV merged: vf pair prefetched one kk ahead ----
            const unsigned short* Vp = Vt[cur][jj];
            u16x8 vf0 = *(const u16x8*)&Vp[lq * 128 + (((0 * 8 + 0 * 2 + hi)) ^ (lq & 15)) * 8];
            u16x8 vf1 = *(const u16x8*)&Vp[lq * 128 + (((1 * 8 + 0 * 2 + hi)) ^ (lq & 15)) * 8];
            __builtin_amdgcn_s_setprio(1);
            #pragma unroll
            for (int kk = 0; kk < 4; ++kk) {
                u16x8 nf0, nf1;
                if (kk < 3) {
                    int s0 = (0 * 8 + (kk + 1) * 2 + hi) ^ (lq & 15);
                    int s1 = (1 * 8 + (kk + 1) * 2 + hi) ^ (lq & 15);
                    nf0 = *(const u16x8*)&Vp[lq * 128 + s0 * 8];
                    nf1 = *(const u16x8*)&Vp[lq * 128 + s1 * 8];
                }
                osumA = mfma32(paA[kk], onesf, osumA);
                osumB = mfma32(paB[kk], onesf, osumB);
                oA[0] = mfma32(paA[kk], vf0, oA[0]);
                oB[0] = mfma32(paB[kk], vf0, oB[0]);
                oA[1] = mfma32(paA[kk], vf1, oA[1]);
                oB[1] = mfma32(paB[kk], vf1, oB[1]);
                vf0 = nf0; vf1 = nf1;
            }
            __builtin_amdgcn_s_setprio(0);
        }

        __syncthreads();
        cur ^= 1;
    }

    // ---- epilogue: normalize and store both q-blocks ----
    #pragma unroll
    for (int r = 0; r < 16; ++r) {
        int qrow = (r & 3) + 8 * (r >> 2) + 4 * hi;
        float iA = frcp(osumA[r]);
        float iB = frcp(osumB[r]);
        size_t roA = (size_t)(b * 2048 + q0 + qrow) * 1024 + h * 64;
        size_t roB = (size_t)(b * 2048 + q0 + 32 + qrow) * 1024 + h * 64;
        attn[roA + lq]      = f2bf(oA[0][r] * iA);
        attn[roA + 32 + lq] = f2bf(oA[1][r] * iA);
        attn[roB + lq]      = f2bf(oB[0][r] * iB);
        attn[roB + 32 + lq] = f2bf(oB[1][r] * iB);
    }
}

extern "C" void kernel_launch(void* const* d_in, const int* in_sizes, int n_in,
                              void* d_out, int out_size, void* d_ws, size_t ws_size,
                              hipStream_t stream) {
    const float* x     = (const float*)d_in[0];
    const float* w_qkv = (const float*)d_in[1];
    const float* w_out = (const float*)d_in[2];
    const float* b_out = (const float*)d_in[3];
    float* out = (float*)d_out;

    char* ws = (char*)d_ws;
    size_t off = 0;
    auto alloc = [&](size_t bytes) -> void* {
        void* p = ws + off;
        off += (bytes + 255) & ~(size_t)255;
        return p;
    };
    unsigned short* xb    = (unsigned short*)alloc(8192ull * 1024 * 2);  // x bf16; reused as attn-out
    unsigned short* wqkvT = (unsigned short*)alloc(3072ull * 1024 * 2);
    unsigned short* woutT = (unsigned short*)alloc(1024ull * 1024 * 2);
    unsigned short* qkv   = (unsigned short*)alloc(8192ull * 3072 * 2);
    unsigned short* VTs   = (unsigned short*)alloc(64ull * 2048 * 64 * 2);
    if (off > ws_size) return;

    k_prep<<<6144, 256, 0, stream>>>(x, xb, w_qkv, wqkvT, w_out, woutT);
    k_gemm1f<<<dim3(8, 32), 512, 0, stream>>>(xb, wqkvT, qkv, VTs);
    k_attn<<<dim3(8, 64), 256, 0, stream>>>(qkv, VTs, xb);
    k_gemm2<<<dim3(8, 32), 512, 0, stream>>>(xb, woutT, b_out, out);
}